// Round 9
// baseline (317.040 us; speedup 1.0000x reference)
//
#include <hip/hip_runtime.h>
#include <hip/hip_bf16.h>

#define D_MODEL 1024
#define NUM_HEADS 16
#define HEAD_DIM 64
#define BATCH 2
#define SEQ 2048
#define M_TOT (BATCH*SEQ)      // 4096
#define CHUNK 64
#define NCHUNK (SEQ/CHUNK)     // 32
#define LT 68                  // LDS stride (ushorts) for attention tiles

typedef __attribute__((ext_vector_type(8))) short bf16x8;
typedef __attribute__((ext_vector_type(8))) unsigned short us16x8;
typedef __attribute__((ext_vector_type(4))) float f32x4;

__device__ inline ushort f2bf(float f) {
    __hip_bfloat16 h = __float2bfloat16(f);
    return __builtin_bit_cast(ushort, h);
}
__device__ inline float bf2f(ushort u) {
    unsigned int v = ((unsigned int)u) << 16;
    return __builtin_bit_cast(float, v);
}

__device__ inline bf16x8 ld_frag(const ushort* p) {
    struct S { uint2 a, b; };
    S s;
    s.a = *(const uint2*)p;
    s.b = *(const uint2*)(p + 4);
    return __builtin_bit_cast(bf16x8, s);
}

__device__ inline void st16(ushort* dst, uint4 a, uint4 b) {
    *(uint2*)(dst + 0)  = make_uint2(a.x, a.y);
    *(uint2*)(dst + 4)  = make_uint2(a.z, a.w);
    *(uint2*)(dst + 8)  = make_uint2(b.x, b.y);
    *(uint2*)(dst + 12) = make_uint2(b.z, b.w);
}

// async global->LDS, 16B per lane; LDS dst is wave-uniform base + lane*16
__device__ inline void load_lds16(const ushort* g, ushort* l) {
    __builtin_amdgcn_global_load_lds(
        (const __attribute__((address_space(1))) unsigned int*)g,
        (__attribute__((address_space(3))) unsigned int*)l, 16, 0, 0);
}

// ---------------- fused cast fp32 -> bf16 (x|Wq|Wk|Wv|Wo) + decay table ----------------
#define XN (M_TOT * D_MODEL)              // 4194304
#define WN (D_MODEL * D_MODEL)            // 1048576
#define CAST_BLOCKS ((XN + 4 * WN) / 4 / 256)   // 8192
__global__ __launch_bounds__(256) void cast_all_kernel(const float* __restrict__ x,
                                                       const float* __restrict__ Wq,
                                                       const float* __restrict__ Wk,
                                                       const float* __restrict__ Wv,
                                                       const float* __restrict__ Wo,
                                                       ushort* __restrict__ dst,
                                                       const float* __restrict__ gamma,
                                                       float* __restrict__ decay) {
    int bx = blockIdx.x;
    if (bx >= CAST_BLOCKS) {  // decay region: gamma[h]^i
        int idx = (bx - CAST_BLOCKS) * 256 + threadIdx.x;   // 32768 total
        int i = idx >> 4, h = idx & 15;
        decay[idx] = powf(gamma[h], (float)i);
        return;
    }
    size_t o = ((size_t)bx * 256 + threadIdx.x) * 4;
    const float* src;
    if (o < XN)               src = x  + o;
    else if (o < XN + WN)     src = Wq + (o - XN);
    else if (o < XN + 2 * WN) src = Wk + (o - XN - WN);
    else if (o < XN + 3 * WN) src = Wv + (o - XN - 2 * (size_t)WN);
    else                      src = Wo + (o - XN - 3 * (size_t)WN);
    float4 f = *(const float4*)src;
    ushort4 u;
    u.x = f2bf(f.x); u.y = f2bf(f.y); u.z = f2bf(f.z); u.w = f2bf(f.w);
    *(ushort4*)(dst + o) = u;
}

// ---------------- 128x64-tile MFMA GEMM (QKV), register-prefetch pipelined -------------
// C[m,n] = sum_k A[m,k]*Bt[n,k] + bias[n]; Bt = [Wq|Wk|Wv] (3072x1024); bf16 outputs;
// decay folded into buffer 0 (q). grid (48, 32) = 1536 blocks (6/CU), 4 waves (2x2).
// Pipeline: regs hold slice k; per iter: barrier, regs->LDS, barrier, issue loads for
// k+1 (wait lands at next iter's ds_write), compute slice k from LDS. Hides load latency
// behind the ~1100-cycle MFMA phase instead of draining vmcnt(0) at the barrier.
__global__ __launch_bounds__(256) void gemm_qkv(const ushort* __restrict__ A,
                                                const ushort* __restrict__ Bt,
                                                const float* __restrict__ b0,
                                                const float* __restrict__ b1,
                                                const float* __restrict__ b2,
                                                ushort* __restrict__ o0,
                                                ushort* __restrict__ o1,
                                                ushort* __restrict__ o2,
                                                const float* __restrict__ decay) {
    const int K = 1024;
    __shared__ ushort lds[192 * 64];    // 24 KB: A tile (128 rows) + B tile (64 rows)
    int t = threadIdx.x;
    int lane = t & 63, w = t >> 6;
    int bn = blockIdx.x * 64, bm = blockIdx.y * 128;
    int wm = (w >> 1) * 64, wn = (w & 1) * 32;

    int lr = lane >> 3, lc = lane & 7;
    int gcol = lc ^ (lr & 7);           // XOR swizzle: LDS chunk c holds global chunk c^(row&7)
    const ushort* gptr[6];
    int ldsoff[6];
    #pragma unroll
    for (int q = 0; q < 6; q++) {
        int grow = w * 48 + q * 8;      // wave-uniform slab base
        ldsoff[q] = grow * 64 + lr * 64 + lc * 8;   // lane's 16B slot (matches lane*16 layout)
        int row = grow + lr;            // per-lane row within slab
        gptr[q] = (row < 128) ? (A + (size_t)(bm + row) * K + gcol * 8)
                              : (Bt + (size_t)(bn + row - 128) * K + gcol * 8);
    }

    f32x4 acc[4][2];
    #pragma unroll
    for (int i = 0; i < 4; i++)
        #pragma unroll
        for (int j = 0; j < 2; j++)
            acc[i][j] = (f32x4){0.f, 0.f, 0.f, 0.f};

    int mrel = lane & 15, kq = lane >> 4;

    // prologue: load slice 0 into registers
    uint4 pre[6];
    #pragma unroll
    for (int q = 0; q < 6; q++)
        pre[q] = *(const uint4*)gptr[q];

    for (int k0 = 0; k0 < K; k0 += 64) {
        __syncthreads();                 // previous compute done reading LDS
        #pragma unroll
        for (int q = 0; q < 6; q++)
            *(uint4*)(&lds[ldsoff[q]]) = pre[q];
        __syncthreads();                 // LDS tile ready
        if (k0 + 64 < K) {
            #pragma unroll
            for (int q = 0; q < 6; q++)
                pre[q] = *(const uint4*)(gptr[q] + k0 + 64);   // in flight during compute
        }
        #pragma unroll
        for (int s = 0; s < 2; s++) {
            bf16x8 af[4], bfv[2];
            #pragma unroll
            for (int i = 0; i < 4; i++) {
                int row = wm + i * 16 + mrel;
                af[i] = ld_frag(&lds[row * 64 + (((s * 4 + kq) ^ (row & 7)) * 8)]);
            }
            #pragma unroll
            for (int j = 0; j < 2; j++) {
                int row = 128 + wn + j * 16 + mrel;
                bfv[j] = ld_frag(&lds[row * 64 + (((s * 4 + kq) ^ (row & 7)) * 8)]);
            }
            #pragma unroll
            for (int i = 0; i < 4; i++)
                #pragma unroll
                for (int j = 0; j < 2; j++)
                    acc[i][j] = __builtin_amdgcn_mfma_f32_16x16x32_bf16(af[i], bfv[j], acc[i][j], 0, 0, 0);
        }
    }

    // epilogue. C/D layout: col = lane&15, row = (lane>>4)*4 + reg
    int quad = lane >> 4;
    int buf = bn >> 10;
    const float* bias = (buf == 0) ? b0 : (buf == 1) ? b1 : b2;
    ushort* dstv = (buf == 0) ? o0 : (buf == 1) ? o1 : o2;
    int cbase = (bn & 1023) + wn;
    #pragma unroll
    for (int j = 0; j < 2; j++) {
        int cl = cbase + j * 16 + mrel;
        float bv = bias[cl];
        #pragma unroll
        for (int i = 0; i < 4; i++) {
            #pragma unroll
            for (int reg = 0; reg < 4; reg++) {
                int row = bm + wm + i * 16 + quad * 4 + reg;
                float v = acc[i][j][reg] + bv;
                if (buf == 0)
                    v *= decay[(row & (SEQ - 1)) * 16 + (cl >> 6)];
                dstv[(size_t)row * 1024 + cl] = f2bf(v);
            }
        }
    }
}

// ---------------- 64x64-tile MFMA GEMM (Wo): 1024 blocks @ 4/CU (round-7 proven) ------
__global__ __launch_bounds__(256) void gemm64_wo(const ushort* __restrict__ A,
                                                 const ushort* __restrict__ Bt,
                                                 const float* __restrict__ bias,
                                                 float* __restrict__ C) {
    const int K = 1024;
    __shared__ ushort lds_a[64 * 64];   // 8 KB each, XOR-swizzled chunk cols
    __shared__ ushort lds_b[64 * 64];
    int t = threadIdx.x, lane = t & 63, w = t >> 6;
    int bm = blockIdx.y * 64, bn = blockIdx.x * 64;
    int wm = (w >> 1) * 32, wn = (w & 1) * 32;

    int lr = lane >> 3, lc = lane & 7;
    int gcol = lc ^ (lr & 7);
    const ushort* aBase = A  + (size_t)(bm + w * 16 + lr) * K + gcol * 8;
    const ushort* bBase = Bt + (size_t)(bn + w * 16 + lr) * K + gcol * 8;
    ushort* aLds = &lds_a[(w * 16) * 64];
    ushort* bLds = &lds_b[(w * 16) * 64];

    f32x4 acc[2][2];
    #pragma unroll
    for (int i = 0; i < 2; i++)
        #pragma unroll
        for (int j = 0; j < 2; j++)
            acc[i][j] = (f32x4){0.f, 0.f, 0.f, 0.f};

    int mrel = lane & 15, kq = lane >> 4;

    for (int k0 = 0; k0 < K; k0 += 64) {
        load_lds16(aBase + k0, aLds);
        load_lds16(aBase + (size_t)8 * K + k0, aLds + 512);
        load_lds16(bBase + k0, bLds);
        load_lds16(bBase + (size_t)8 * K + k0, bLds + 512);
        __syncthreads();
        #pragma unroll
        for (int s = 0; s < 2; s++) {
            bf16x8 af[2], bfv[2];
            #pragma unroll
            for (int i = 0; i < 2; i++) {
                int row = wm + i * 16 + mrel;
                af[i] = ld_frag(&lds_a[row * 64 + (((s * 4 + kq) ^ (row & 7)) * 8)]);
            }
            #pragma unroll
            for (int j = 0; j < 2; j++) {
                int row = wn + j * 16 + mrel;
                bfv[j] = ld_frag(&lds_b[row * 64 + (((s * 4 + kq) ^ (row & 7)) * 8)]);
            }
            #pragma unroll
            for (int i = 0; i < 2; i++)
                #pragma unroll
                for (int j = 0; j < 2; j++)
                    acc[i][j] = __builtin_amdgcn_mfma_f32_16x16x32_bf16(af[i], bfv[j], acc[i][j], 0, 0, 0);
        }
        __syncthreads();
    }

    int quad = lane >> 4;
    #pragma unroll
    for (int j = 0; j < 2; j++) {
        int col = bn + wn + j * 16 + mrel;
        float bv = bias[col];
        #pragma unroll
        for (int i = 0; i < 2; i++) {
            #pragma unroll
            for (int reg = 0; reg < 4; reg++) {
                int row = bm + wm + i * 16 + quad * 4 + reg;
                C[(size_t)row * 1024 + col] = acc[i][j][reg] + bv;
            }
        }
    }
}

// ---------------- per-chunk KV state (MFMA) -> bf16, coalesced via LDS ----------------
__global__ __launch_bounds__(256) void chunk_kv_mfma(const ushort* __restrict__ kp,
                                                     const ushort* __restrict__ vp,
                                                     ushort* __restrict__ statesb) {
    __shared__ ushort Kt[64 * LT];
    __shared__ ushort Vt[64 * LT];
    int bx = blockIdx.x;
    int c = bx & 31, h = (bx >> 5) & 15, b = bx >> 9;
    int t = threadIdx.x, lane = t & 63, w = t >> 6;
    size_t rowbase = (size_t)(b * SEQ + c * 64);
    int r = t >> 2, cc = t & 3;
    const uint4* gk = (const uint4*)(kp + (rowbase + r) * D_MODEL + h * 64 + cc * 16);
    const uint4* gv = (const uint4*)(vp + (rowbase + r) * D_MODEL + h * 64 + cc * 16);
    uint4 k0 = gk[0], k1 = gk[1], v0 = gv[0], v1 = gv[1];
    {
        us16x8 ka = __builtin_bit_cast(us16x8, k0), kb = __builtin_bit_cast(us16x8, k1);
        us16x8 va = __builtin_bit_cast(us16x8, v0), vb = __builtin_bit_cast(us16x8, v1);
        #pragma unroll
        for (int i = 0; i < 8; i++) {
            Kt[(cc * 16 + i) * LT + r]     = ka[i];
            Kt[(cc * 16 + 8 + i) * LT + r] = kb[i];
            Vt[(cc * 16 + i) * LT + r]     = va[i];
            Vt[(cc * 16 + 8 + i) * LT + r] = vb[i];
        }
    }
    __syncthreads();
    int mrel = lane & 15, q8 = (lane >> 4) * 8, band = w * 16, quad = lane >> 4;
    bf16x8 af[2];
    af[0] = ld_frag(&Vt[(band + mrel) * LT + q8]);
    af[1] = ld_frag(&Vt[(band + mrel) * LT + 32 + q8]);
    f32x4 acc[4];
    #pragma unroll
    for (int dt = 0; dt < 4; dt++) acc[dt] = (f32x4){0.f, 0.f, 0.f, 0.f};
    #pragma unroll
    for (int dt = 0; dt < 4; dt++)
        #pragma unroll
        for (int kk = 0; kk < 2; kk++)
            acc[dt] = __builtin_amdgcn_mfma_f32_16x16x32_bf16(
                af[kk], ld_frag(&Kt[(dt * 16 + mrel) * LT + kk * 32 + q8]), acc[dt], 0, 0, 0);
    __syncthreads();   // all waves done reading Kt/Vt
    #pragma unroll
    for (int dt = 0; dt < 4; dt++)
        #pragma unroll
        for (int reg = 0; reg < 4; reg++)
            Kt[(band + quad * 4 + reg) * LT + dt * 16 + mrel] = f2bf(acc[dt][reg]);
    __syncthreads();
    {
        bf16x8 s0 = ld_frag(&Kt[r * LT + cc * 16]);
        bf16x8 s1 = ld_frag(&Kt[r * LT + cc * 16 + 8]);
        uint4* dst = (uint4*)(statesb + (size_t)bx * 4096 + r * 64 + cc * 16);
        dst[0] = __builtin_bit_cast(uint4, s0);
        dst[1] = __builtin_bit_cast(uint4, s1);
    }
}

// ---------------- exclusive prefix over chunks, bf16 in place ----------------
__global__ __launch_bounds__(256) void prefix_kernel(ushort* __restrict__ statesb) {
    int bh = blockIdx.y;
    int e = blockIdx.x * 256 + threadIdx.x;
    ushort* p = statesb + (size_t)bh * NCHUNK * 4096 + e;
    float run = 0.f;
    for (int cb = 0; cb < NCHUNK; cb += 8) {
        float vals[8];
        #pragma unroll
        for (int u = 0; u < 8; u++) vals[u] = bf2f(p[(size_t)(cb + u) * 4096]);
        #pragma unroll
        for (int u = 0; u < 8; u++) {
            p[(size_t)(cb + u) * 4096] = f2bf(run);
            run += vals[u];
        }
    }
}

// ---------------- per-chunk attention (MFMA): O = Q'·S^T + causal(Q'K^T)·V ----------------
__global__ __launch_bounds__(256) void attn_mfma(const ushort* __restrict__ qp,
                                                 const ushort* __restrict__ kp,
                                                 const ushort* __restrict__ vp,
                                                 const ushort* __restrict__ statesb,
                                                 ushort* __restrict__ attn_out) {
    __shared__ ushort Qs[64 * LT];
    __shared__ ushort Ks[64 * LT];
    __shared__ ushort Vt[64 * LT];
    __shared__ ushort St[64 * LT];
    __shared__ ushort Ps[64 * LT];
    int bx = blockIdx.x;
    int c = bx & 31, h = (bx >> 5) & 15, b = bx >> 9;
    int t = threadIdx.x, lane = t & 63, w = t >> 6;
    size_t rowbase = (size_t)(b * SEQ + c * 64);
    int r = t >> 2, cc = t & 3;
    {
        const uint4* gq = (const uint4*)(qp + (rowbase + r) * D_MODEL + h * 64 + cc * 16);
        const uint4* gk = (const uint4*)(kp + (rowbase + r) * D_MODEL + h * 64 + cc * 16);
        const uint4* gv = (const uint4*)(vp + (rowbase + r) * D_MODEL + h * 64 + cc * 16);
        const uint4* gs = (const uint4*)(statesb + (size_t)bx * 4096 + t * 16);
        uint4 q0 = gq[0], q1 = gq[1];
        uint4 k0 = gk[0], k1 = gk[1];
        uint4 v0 = gv[0], v1 = gv[1];
        uint4 s0 = gs[0], s1 = gs[1];
        st16(&Qs[r * LT + cc * 16], q0, q1);
        st16(&Ks[r * LT + cc * 16], k0, k1);
        st16(&St[r * LT + cc * 16], s0, s1);
        us16x8 va = __builtin_bit_cast(us16x8, v0), vb = __builtin_bit_cast(us16x8, v1);
        #pragma unroll
        for (int i = 0; i < 8; i++) {
            Vt[(cc * 16 + i) * LT + r]     = va[i];
            Vt[(cc * 16 + 8 + i) * LT + r] = vb[i];
        }
    }
    __syncthreads();

    int mrel = lane & 15, q8 = (lane >> 4) * 8, quad = lane >> 4, band = w * 16;
    bf16x8 af[2];
    af[0] = ld_frag(&Qs[(band + mrel) * LT + q8]);
    af[1] = ld_frag(&Qs[(band + mrel) * LT + 32 + q8]);

    f32x4 oacc[4];
    #pragma unroll
    for (int dt = 0; dt < 4; dt++) oacc[dt] = (f32x4){0.f, 0.f, 0.f, 0.f};
    #pragma unroll
    for (int dt = 0; dt < 4; dt++)
        #pragma unroll
        for (int kk = 0; kk < 2; kk++)
            oacc[dt] = __builtin_amdgcn_mfma_f32_16x16x32_bf16(
                af[kk], ld_frag(&St[(dt * 16 + mrel) * LT + kk * 32 + q8]), oacc[dt], 0, 0, 0);

    f32x4 pacc[4];
    #pragma unroll
    for (int jt = 0; jt < 4; jt++) pacc[jt] = (f32x4){0.f, 0.f, 0.f, 0.f};
    #pragma unroll
    for (int jt = 0; jt < 4; jt++) {
        if (jt <= w) {
            #pragma unroll
            for (int kk = 0; kk < 2; kk++)
                pacc[jt] = __builtin_amdgcn_mfma_f32_16x16x32_bf16(
                    af[kk], ld_frag(&Ks[(jt * 16 + mrel) * LT + kk * 32 + q8]), pacc[jt], 0, 0, 0);
        }
    }
    #pragma unroll
    for (int jt = 0; jt < 4; jt++) {
        #pragma unroll
        for (int reg = 0; reg < 4; reg++) {
            int i = band + quad * 4 + reg;
            int j = jt * 16 + mrel;
            float val = (jt <= w && j <= i) ? pacc[jt][reg] : 0.f;
            Ps[i * LT + j] = f2bf(val);
        }
    }
    __syncthreads();

    bf16x8 pf0 = ld_frag(&Ps[(band + mrel) * LT + q8]);
    #pragma unroll
    for (int dt = 0; dt < 4; dt++)
        oacc[dt] = __builtin_amdgcn_mfma_f32_16x16x32_bf16(
            pf0, ld_frag(&Vt[(dt * 16 + mrel) * LT + q8]), oacc[dt], 0, 0, 0);
    if (w >= 2) {
        bf16x8 pf1 = ld_frag(&Ps[(band + mrel) * LT + 32 + q8]);
        #pragma unroll
        for (int dt = 0; dt < 4; dt++)
            oacc[dt] = __builtin_amdgcn_mfma_f32_16x16x32_bf16(
                pf1, ld_frag(&Vt[(dt * 16 + mrel) * LT + 32 + q8]), oacc[dt], 0, 0, 0);
    }

    #pragma unroll
    for (int dt = 0; dt < 4; dt++) {
        #pragma unroll
        for (int reg = 0; reg < 4; reg++) {
            size_t row = rowbase + band + quad * 4 + reg;
            int col = h * 64 + dt * 16 + mrel;
            attn_out[row * D_MODEL + col] = f2bf(oacc[dt][reg]);
        }
    }
}

// ---------------- host launch ----------------
extern "C" void kernel_launch(void* const* d_in, const int* in_sizes, int n_in,
                              void* d_out, int out_size, void* d_ws, size_t ws_size,
                              hipStream_t stream) {
    (void)in_sizes; (void)n_in; (void)out_size; (void)ws_size;
    const float* x  = (const float*)d_in[0];
    const float* Wq = (const float*)d_in[1];
    const float* bq = (const float*)d_in[2];
    const float* Wk = (const float*)d_in[3];
    const float* bk = (const float*)d_in[4];
    const float* Wv = (const float*)d_in[5];
    const float* bv = (const float*)d_in[6];
    const float* Wo = (const float*)d_in[7];
    const float* bo = (const float*)d_in[8];
    const float* gamma = (const float*)d_in[9];
    float* out = (float*)d_out;

    uint8_t* w = (uint8_t*)d_ws;
    ushort* xb    = (ushort*)w; w += (size_t)XN * 2;            // 8 MB; reused as bf16 attn
    ushort* wqkvb = (ushort*)w; w += (size_t)3 * WN * 2;        // 6 MB
    ushort* wob   = (ushort*)w; w += (size_t)WN * 2;            // 2 MB
    ushort* qb  = (ushort*)w; w += (size_t)XN * 2;              // 8 MB
    ushort* kb  = (ushort*)w; w += (size_t)XN * 2;
    ushort* vb  = (ushort*)w; w += (size_t)XN * 2;
    ushort* statesb = (ushort*)w; w += (size_t)BATCH * NUM_HEADS * NCHUNK * 4096 * 2; // 8 MB
    float*  decay = (float*)w; w += (size_t)SEQ * NUM_HEADS * 4;

    cast_all_kernel<<<CAST_BLOCKS + (SEQ * NUM_HEADS) / 256, 256, 0, stream>>>(
        x, Wq, Wk, Wv, Wo, xb, gamma, decay);

    // fused QKV projection: 128x64 tiles, register-prefetch pipeline, bf16 out
    gemm_qkv<<<dim3(3072 / 64, M_TOT / 128), 256, 0, stream>>>(
        xb, wqkvb, bq, bk, bv, qb, kb, vb, decay);

    int nblk = BATCH * NUM_HEADS * NCHUNK;  // 1024
    chunk_kv_mfma<<<nblk, 256, 0, stream>>>(kb, vb, statesb);
    prefix_kernel<<<dim3(16, 32), 256, 0, stream>>>(statesb);
    attn_mfma<<<nblk, 256, 0, stream>>>(qb, kb, vb, statesb, xb);   // bf16 attn into xb

    // output projection: 64x64 tiles -> 1024 blocks (4/CU), fp32 out (round-7 proven)
    gemm64_wo<<<dim3(1024 / 64, M_TOT / 64), 256, 0, stream>>>(xb, wob, bo, out);
}

// Round 10
// 169.831 us; speedup vs baseline: 1.8668x; 1.8668x over previous
//
#include <hip/hip_runtime.h>
#include <hip/hip_bf16.h>

#define D_MODEL 1024
#define NUM_HEADS 16
#define HEAD_DIM 64
#define BATCH 2
#define SEQ 2048
#define M_TOT (BATCH*SEQ)      // 4096
#define CHUNK 64
#define NCHUNK (SEQ/CHUNK)     // 32
#define LT 68                  // LDS stride (ushorts) for attention tiles

typedef __attribute__((ext_vector_type(8))) short bf16x8;
typedef __attribute__((ext_vector_type(8))) unsigned short us16x8;
typedef __attribute__((ext_vector_type(4))) float f32x4;

__device__ inline ushort f2bf(float f) {
    __hip_bfloat16 h = __float2bfloat16(f);
    return __builtin_bit_cast(ushort, h);
}
__device__ inline float bf2f(ushort u) {
    unsigned int v = ((unsigned int)u) << 16;
    return __builtin_bit_cast(float, v);
}

__device__ inline bf16x8 ld_frag(const ushort* p) {
    struct S { uint2 a, b; };
    S s;
    s.a = *(const uint2*)p;
    s.b = *(const uint2*)(p + 4);
    return __builtin_bit_cast(bf16x8, s);
}

__device__ inline void st16(ushort* dst, uint4 a, uint4 b) {
    *(uint2*)(dst + 0)  = make_uint2(a.x, a.y);
    *(uint2*)(dst + 4)  = make_uint2(a.z, a.w);
    *(uint2*)(dst + 8)  = make_uint2(b.x, b.y);
    *(uint2*)(dst + 12) = make_uint2(b.z, b.w);
}

// async global->LDS, 16B per lane; LDS dst is wave-uniform base + lane*16
__device__ inline void load_lds16(const ushort* g, ushort* l) {
    __builtin_amdgcn_global_load_lds(
        (const __attribute__((address_space(1))) unsigned int*)g,
        (__attribute__((address_space(3))) unsigned int*)l, 16, 0, 0);
}

// ---------------- fused cast fp32 -> bf16 (x|Wq|Wk|Wv|Wo) + decay table ----------------
#define XN (M_TOT * D_MODEL)              // 4194304
#define WN (D_MODEL * D_MODEL)            // 1048576
#define CAST_BLOCKS ((XN + 4 * WN) / 4 / 256)   // 8192
__global__ __launch_bounds__(256) void cast_all_kernel(const float* __restrict__ x,
                                                       const float* __restrict__ Wq,
                                                       const float* __restrict__ Wk,
                                                       const float* __restrict__ Wv,
                                                       const float* __restrict__ Wo,
                                                       ushort* __restrict__ dst,
                                                       const float* __restrict__ gamma,
                                                       float* __restrict__ decay) {
    int bx = blockIdx.x;
    if (bx >= CAST_BLOCKS) {  // decay region: gamma[h]^i
        int idx = (bx - CAST_BLOCKS) * 256 + threadIdx.x;   // 32768 total
        int i = idx >> 4, h = idx & 15;
        decay[idx] = powf(gamma[h], (float)i);
        return;
    }
    size_t o = ((size_t)bx * 256 + threadIdx.x) * 4;
    const float* src;
    if (o < XN)               src = x  + o;
    else if (o < XN + WN)     src = Wq + (o - XN);
    else if (o < XN + 2 * WN) src = Wk + (o - XN - WN);
    else if (o < XN + 3 * WN) src = Wv + (o - XN - 2 * (size_t)WN);
    else                      src = Wo + (o - XN - 3 * (size_t)WN);
    float4 f = *(const float4*)src;
    ushort4 u;
    u.x = f2bf(f.x); u.y = f2bf(f.y); u.z = f2bf(f.z); u.w = f2bf(f.w);
    *(ushort4*)(dst + o) = u;
}

// ---------------- 128x64-tile MFMA GEMM (QKV): round-7 proven (43.7 us) ----------------
// C[m,n] = sum_k A[m,k]*Bt[n,k] + bias[n]; Bt = [Wq|Wk|Wv] (3072x1024); bf16 outputs;
// decay folded into buffer 0 (q). grid (48, 32) = 1536 blocks (6/CU), 4 waves (2x2).
// NOTE (r9 lesson): do NOT hold prefetch data in VGPR arrays across __syncthreads here —
// the compiler spills them to scratch (WRITE_SIZE exploded 27->515 MB, 4.5x slower).
__global__ __launch_bounds__(256) void gemm_qkv(const ushort* __restrict__ A,
                                                const ushort* __restrict__ Bt,
                                                const float* __restrict__ b0,
                                                const float* __restrict__ b1,
                                                const float* __restrict__ b2,
                                                ushort* __restrict__ o0,
                                                ushort* __restrict__ o1,
                                                ushort* __restrict__ o2,
                                                const float* __restrict__ decay) {
    const int K = 1024;
    __shared__ ushort lds[192 * 64];    // 24 KB: A tile (128 rows) + B tile (64 rows)
    int t = threadIdx.x;
    int lane = t & 63, w = t >> 6;
    int bn = blockIdx.x * 64, bm = blockIdx.y * 128;
    int wm = (w >> 1) * 64, wn = (w & 1) * 32;

    int lr = lane >> 3, lc = lane & 7;
    int gcol = lc ^ (lr & 7);           // XOR swizzle: LDS chunk c holds global chunk c^(row&7)
    const ushort* gptr[6];
    int ldsoff[6];
    #pragma unroll
    for (int q = 0; q < 6; q++) {
        int grow = w * 48 + q * 8;      // wave-uniform slab base
        ldsoff[q] = grow * 64;
        int row = grow + lr;            // per-lane row within slab
        gptr[q] = (row < 128) ? (A + (size_t)(bm + row) * K + gcol * 8)
                              : (Bt + (size_t)(bn + row - 128) * K + gcol * 8);
    }

    f32x4 acc[4][2];
    #pragma unroll
    for (int i = 0; i < 4; i++)
        #pragma unroll
        for (int j = 0; j < 2; j++)
            acc[i][j] = (f32x4){0.f, 0.f, 0.f, 0.f};

    int mrel = lane & 15, kq = lane >> 4;

    for (int k0 = 0; k0 < K; k0 += 64) {
        #pragma unroll
        for (int q = 0; q < 6; q++)
            load_lds16(gptr[q] + k0, &lds[ldsoff[q]]);
        __syncthreads();
        #pragma unroll
        for (int s = 0; s < 2; s++) {
            bf16x8 af[4], bfv[2];
            #pragma unroll
            for (int i = 0; i < 4; i++) {
                int row = wm + i * 16 + mrel;
                af[i] = ld_frag(&lds[row * 64 + (((s * 4 + kq) ^ (row & 7)) * 8)]);
            }
            #pragma unroll
            for (int j = 0; j < 2; j++) {
                int row = 128 + wn + j * 16 + mrel;
                bfv[j] = ld_frag(&lds[row * 64 + (((s * 4 + kq) ^ (row & 7)) * 8)]);
            }
            #pragma unroll
            for (int i = 0; i < 4; i++)
                #pragma unroll
                for (int j = 0; j < 2; j++)
                    acc[i][j] = __builtin_amdgcn_mfma_f32_16x16x32_bf16(af[i], bfv[j], acc[i][j], 0, 0, 0);
        }
        __syncthreads();
    }

    // epilogue. C/D layout: col = lane&15, row = (lane>>4)*4 + reg
    int quad = lane >> 4;
    int buf = bn >> 10;
    const float* bias = (buf == 0) ? b0 : (buf == 1) ? b1 : b2;
    ushort* dstv = (buf == 0) ? o0 : (buf == 1) ? o1 : o2;
    int cbase = (bn & 1023) + wn;
    #pragma unroll
    for (int j = 0; j < 2; j++) {
        int cl = cbase + j * 16 + mrel;
        float bv = bias[cl];
        #pragma unroll
        for (int i = 0; i < 4; i++) {
            #pragma unroll
            for (int reg = 0; reg < 4; reg++) {
                int row = bm + wm + i * 16 + quad * 4 + reg;
                float v = acc[i][j][reg] + bv;
                if (buf == 0)
                    v *= decay[(row & (SEQ - 1)) * 16 + (cl >> 6)];
                dstv[(size_t)row * 1024 + cl] = f2bf(v);
            }
        }
    }
}

// ---------------- 64x64-tile Wo GEMM, BK=128: 8 iterations, 1024 blocks @ 4/CU --------
// Wall time of these latency-bound GEMMs ~ K-iterations x barrier drain (r8 lesson), so
// halve the iterations. LDS 2x16 KB = 32 KB -> still 4 blocks/CU (128 KB < 160 KB).
// Staging: 4-row slabs, lane L -> row base+(L>>4), chunk L&15 holding global chunk
// (L&15)^(row&7). grid (16, 64), 256 threads (4 waves, 2x2 of 16x16 frags).
__global__ __launch_bounds__(256) void gemm64_wo(const ushort* __restrict__ A,
                                                 const ushort* __restrict__ Bt,
                                                 const float* __restrict__ bias,
                                                 float* __restrict__ C) {
    const int K = 1024;
    __shared__ ushort lds_a[64 * 128];   // 16 KB
    __shared__ ushort lds_b[64 * 128];   // 16 KB
    int t = threadIdx.x, lane = t & 63, w = t >> 6;
    int bm = blockIdx.y * 64, bn = blockIdx.x * 64;
    int wm = (w >> 1) * 32, wn = (w & 1) * 32;

    int lr4 = lane >> 4;        // row within 4-row instruction group (0..3)
    int lc16 = lane & 15;       // chunk 0..15
    const ushort* aP[4];
    const ushort* bP[4];
    ushort* aL[4];
    ushort* bL[4];
    #pragma unroll
    for (int s = 0; s < 4; s++) {
        int rowRel = s * 4 + lr4;              // 0..15 within wave's 16-row band
        int gc = lc16 ^ (rowRel & 7);          // XOR swizzle (16 chunks, low-3-bit parity)
        aP[s] = A  + (size_t)(bm + w * 16 + rowRel) * K + gc * 8;
        bP[s] = Bt + (size_t)(bn + w * 16 + rowRel) * K + gc * 8;
        aL[s] = &lds_a[(w * 16 + s * 4) * 128];
        bL[s] = &lds_b[(w * 16 + s * 4) * 128];
    }

    f32x4 acc[2][2];
    #pragma unroll
    for (int i = 0; i < 2; i++)
        #pragma unroll
        for (int j = 0; j < 2; j++)
            acc[i][j] = (f32x4){0.f, 0.f, 0.f, 0.f};

    int mrel = lane & 15, kq = lane >> 4;

    for (int k0 = 0; k0 < K; k0 += 128) {
        #pragma unroll
        for (int s = 0; s < 4; s++) {
            load_lds16(aP[s] + k0, aL[s]);
            load_lds16(bP[s] + k0, bL[s]);
        }
        __syncthreads();
        #pragma unroll
        for (int s = 0; s < 4; s++) {       // 4 K-steps of 32 within the 128-wide tile
            bf16x8 af[2], bfv[2];
            #pragma unroll
            for (int i = 0; i < 2; i++) {
                int row = wm + i * 16 + mrel;
                af[i] = ld_frag(&lds_a[row * 128 + (((s * 4 + kq) ^ (row & 7)) * 8)]);
            }
            #pragma unroll
            for (int j = 0; j < 2; j++) {
                int row = wn + j * 16 + mrel;
                bfv[j] = ld_frag(&lds_b[row * 128 + (((s * 4 + kq) ^ (row & 7)) * 8)]);
            }
            #pragma unroll
            for (int i = 0; i < 2; i++)
                #pragma unroll
                for (int j = 0; j < 2; j++)
                    acc[i][j] = __builtin_amdgcn_mfma_f32_16x16x32_bf16(af[i], bfv[j], acc[i][j], 0, 0, 0);
        }
        __syncthreads();
    }

    int quad = lane >> 4;
    #pragma unroll
    for (int j = 0; j < 2; j++) {
        int col = bn + wn + j * 16 + mrel;
        float bv = bias[col];
        #pragma unroll
        for (int i = 0; i < 2; i++) {
            #pragma unroll
            for (int reg = 0; reg < 4; reg++) {
                int row = bm + wm + i * 16 + quad * 4 + reg;
                C[(size_t)row * 1024 + col] = acc[i][j][reg] + bv;
            }
        }
    }
}

// ---------------- per-chunk KV state (MFMA) -> bf16, coalesced via LDS ----------------
__global__ __launch_bounds__(256) void chunk_kv_mfma(const ushort* __restrict__ kp,
                                                     const ushort* __restrict__ vp,
                                                     ushort* __restrict__ statesb) {
    __shared__ ushort Kt[64 * LT];
    __shared__ ushort Vt[64 * LT];
    int bx = blockIdx.x;
    int c = bx & 31, h = (bx >> 5) & 15, b = bx >> 9;
    int t = threadIdx.x, lane = t & 63, w = t >> 6;
    size_t rowbase = (size_t)(b * SEQ + c * 64);
    int r = t >> 2, cc = t & 3;
    const uint4* gk = (const uint4*)(kp + (rowbase + r) * D_MODEL + h * 64 + cc * 16);
    const uint4* gv = (const uint4*)(vp + (rowbase + r) * D_MODEL + h * 64 + cc * 16);
    uint4 k0 = gk[0], k1 = gk[1], v0 = gv[0], v1 = gv[1];
    {
        us16x8 ka = __builtin_bit_cast(us16x8, k0), kb = __builtin_bit_cast(us16x8, k1);
        us16x8 va = __builtin_bit_cast(us16x8, v0), vb = __builtin_bit_cast(us16x8, v1);
        #pragma unroll
        for (int i = 0; i < 8; i++) {
            Kt[(cc * 16 + i) * LT + r]     = ka[i];
            Kt[(cc * 16 + 8 + i) * LT + r] = kb[i];
            Vt[(cc * 16 + i) * LT + r]     = va[i];
            Vt[(cc * 16 + 8 + i) * LT + r] = vb[i];
        }
    }
    __syncthreads();
    int mrel = lane & 15, q8 = (lane >> 4) * 8, band = w * 16, quad = lane >> 4;
    bf16x8 af[2];
    af[0] = ld_frag(&Vt[(band + mrel) * LT + q8]);
    af[1] = ld_frag(&Vt[(band + mrel) * LT + 32 + q8]);
    f32x4 acc[4];
    #pragma unroll
    for (int dt = 0; dt < 4; dt++) acc[dt] = (f32x4){0.f, 0.f, 0.f, 0.f};
    #pragma unroll
    for (int dt = 0; dt < 4; dt++)
        #pragma unroll
        for (int kk = 0; kk < 2; kk++)
            acc[dt] = __builtin_amdgcn_mfma_f32_16x16x32_bf16(
                af[kk], ld_frag(&Kt[(dt * 16 + mrel) * LT + kk * 32 + q8]), acc[dt], 0, 0, 0);
    __syncthreads();   // all waves done reading Kt/Vt
    #pragma unroll
    for (int dt = 0; dt < 4; dt++)
        #pragma unroll
        for (int reg = 0; reg < 4; reg++)
            Kt[(band + quad * 4 + reg) * LT + dt * 16 + mrel] = f2bf(acc[dt][reg]);
    __syncthreads();
    {
        bf16x8 s0 = ld_frag(&Kt[r * LT + cc * 16]);
        bf16x8 s1 = ld_frag(&Kt[r * LT + cc * 16 + 8]);
        uint4* dst = (uint4*)(statesb + (size_t)bx * 4096 + r * 64 + cc * 16);
        dst[0] = __builtin_bit_cast(uint4, s0);
        dst[1] = __builtin_bit_cast(uint4, s1);
    }
}

// ---------------- exclusive prefix over chunks, bf16 in place ----------------
__global__ __launch_bounds__(256) void prefix_kernel(ushort* __restrict__ statesb) {
    int bh = blockIdx.y;
    int e = blockIdx.x * 256 + threadIdx.x;
    ushort* p = statesb + (size_t)bh * NCHUNK * 4096 + e;
    float run = 0.f;
    for (int cb = 0; cb < NCHUNK; cb += 8) {
        float vals[8];
        #pragma unroll
        for (int u = 0; u < 8; u++) vals[u] = bf2f(p[(size_t)(cb + u) * 4096]);
        #pragma unroll
        for (int u = 0; u < 8; u++) {
            p[(size_t)(cb + u) * 4096] = f2bf(run);
            run += vals[u];
        }
    }
}

// ---------------- per-chunk attention (MFMA): O = Q'·S^T + causal(Q'K^T)·V ----------------
__global__ __launch_bounds__(256) void attn_mfma(const ushort* __restrict__ qp,
                                                 const ushort* __restrict__ kp,
                                                 const ushort* __restrict__ vp,
                                                 const ushort* __restrict__ statesb,
                                                 ushort* __restrict__ attn_out) {
    __shared__ ushort Qs[64 * LT];
    __shared__ ushort Ks[64 * LT];
    __shared__ ushort Vt[64 * LT];
    __shared__ ushort St[64 * LT];
    __shared__ ushort Ps[64 * LT];
    int bx = blockIdx.x;
    int c = bx & 31, h = (bx >> 5) & 15, b = bx >> 9;
    int t = threadIdx.x, lane = t & 63, w = t >> 6;
    size_t rowbase = (size_t)(b * SEQ + c * 64);
    int r = t >> 2, cc = t & 3;
    {
        const uint4* gq = (const uint4*)(qp + (rowbase + r) * D_MODEL + h * 64 + cc * 16);
        const uint4* gk = (const uint4*)(kp + (rowbase + r) * D_MODEL + h * 64 + cc * 16);
        const uint4* gv = (const uint4*)(vp + (rowbase + r) * D_MODEL + h * 64 + cc * 16);
        const uint4* gs = (const uint4*)(statesb + (size_t)bx * 4096 + t * 16);
        uint4 q0 = gq[0], q1 = gq[1];
        uint4 k0 = gk[0], k1 = gk[1];
        uint4 v0 = gv[0], v1 = gv[1];
        uint4 s0 = gs[0], s1 = gs[1];
        st16(&Qs[r * LT + cc * 16], q0, q1);
        st16(&Ks[r * LT + cc * 16], k0, k1);
        st16(&St[r * LT + cc * 16], s0, s1);
        us16x8 va = __builtin_bit_cast(us16x8, v0), vb = __builtin_bit_cast(us16x8, v1);
        #pragma unroll
        for (int i = 0; i < 8; i++) {
            Vt[(cc * 16 + i) * LT + r]     = va[i];
            Vt[(cc * 16 + 8 + i) * LT + r] = vb[i];
        }
    }
    __syncthreads();

    int mrel = lane & 15, q8 = (lane >> 4) * 8, quad = lane >> 4, band = w * 16;
    bf16x8 af[2];
    af[0] = ld_frag(&Qs[(band + mrel) * LT + q8]);
    af[1] = ld_frag(&Qs[(band + mrel) * LT + 32 + q8]);

    f32x4 oacc[4];
    #pragma unroll
    for (int dt = 0; dt < 4; dt++) oacc[dt] = (f32x4){0.f, 0.f, 0.f, 0.f};
    #pragma unroll
    for (int dt = 0; dt < 4; dt++)
        #pragma unroll
        for (int kk = 0; kk < 2; kk++)
            oacc[dt] = __builtin_amdgcn_mfma_f32_16x16x32_bf16(
                af[kk], ld_frag(&St[(dt * 16 + mrel) * LT + kk * 32 + q8]), oacc[dt], 0, 0, 0);

    f32x4 pacc[4];
    #pragma unroll
    for (int jt = 0; jt < 4; jt++) pacc[jt] = (f32x4){0.f, 0.f, 0.f, 0.f};
    #pragma unroll
    for (int jt = 0; jt < 4; jt++) {
        if (jt <= w) {
            #pragma unroll
            for (int kk = 0; kk < 2; kk++)
                pacc[jt] = __builtin_amdgcn_mfma_f32_16x16x32_bf16(
                    af[kk], ld_frag(&Ks[(jt * 16 + mrel) * LT + kk * 32 + q8]), pacc[jt], 0, 0, 0);
        }
    }
    #pragma unroll
    for (int jt = 0; jt < 4; jt++) {
        #pragma unroll
        for (int reg = 0; reg < 4; reg++) {
            int i = band + quad * 4 + reg;
            int j = jt * 16 + mrel;
            float val = (jt <= w && j <= i) ? pacc[jt][reg] : 0.f;
            Ps[i * LT + j] = f2bf(val);
        }
    }
    __syncthreads();

    bf16x8 pf0 = ld_frag(&Ps[(band + mrel) * LT + q8]);
    #pragma unroll
    for (int dt = 0; dt < 4; dt++)
        oacc[dt] = __builtin_amdgcn_mfma_f32_16x16x32_bf16(
            pf0, ld_frag(&Vt[(dt * 16 + mrel) * LT + q8]), oacc[dt], 0, 0, 0);
    if (w >= 2) {
        bf16x8 pf1 = ld_frag(&Ps[(band + mrel) * LT + 32 + q8]);
        #pragma unroll
        for (int dt = 0; dt < 4; dt++)
            oacc[dt] = __builtin_amdgcn_mfma_f32_16x16x32_bf16(
                pf1, ld_frag(&Vt[(dt * 16 + mrel) * LT + 32 + q8]), oacc[dt], 0, 0, 0);
    }

    #pragma unroll
    for (int dt = 0; dt < 4; dt++) {
        #pragma unroll
        for (int reg = 0; reg < 4; reg++) {
            size_t row = rowbase + band + quad * 4 + reg;
            int col = h * 64 + dt * 16 + mrel;
            attn_out[row * D_MODEL + col] = f2bf(oacc[dt][reg]);
        }
    }
}

// ---------------- host launch ----------------
extern "C" void kernel_launch(void* const* d_in, const int* in_sizes, int n_in,
                              void* d_out, int out_size, void* d_ws, size_t ws_size,
                              hipStream_t stream) {
    (void)in_sizes; (void)n_in; (void)out_size; (void)ws_size;
    const float* x  = (const float*)d_in[0];
    const float* Wq = (const float*)d_in[1];
    const float* bq = (const float*)d_in[2];
    const float* Wk = (const float*)d_in[3];
    const float* bk = (const float*)d_in[4];
    const float* Wv = (const float*)d_in[5];
    const float* bv = (const float*)d_in[6];
    const float* Wo = (const float*)d_in[7];
    const float* bo = (const float*)d_in[8];
    const float* gamma = (const float*)d_in[9];
    float* out = (float*)d_out;

    uint8_t* w = (uint8_t*)d_ws;
    ushort* xb    = (ushort*)w; w += (size_t)XN * 2;            // 8 MB; reused as bf16 attn
    ushort* wqkvb = (ushort*)w; w += (size_t)3 * WN * 2;        // 6 MB
    ushort* wob   = (ushort*)w; w += (size_t)WN * 2;            // 2 MB
    ushort* qb  = (ushort*)w; w += (size_t)XN * 2;              // 8 MB
    ushort* kb  = (ushort*)w; w += (size_t)XN * 2;
    ushort* vb  = (ushort*)w; w += (size_t)XN * 2;
    ushort* statesb = (ushort*)w; w += (size_t)BATCH * NUM_HEADS * NCHUNK * 4096 * 2; // 8 MB
    float*  decay = (float*)w; w += (size_t)SEQ * NUM_HEADS * 4;

    cast_all_kernel<<<CAST_BLOCKS + (SEQ * NUM_HEADS) / 256, 256, 0, stream>>>(
        x, Wq, Wk, Wv, Wo, xb, gamma, decay);

    // fused QKV projection: 128x64 tiles (round-7 proven), bf16 out, decay in q
    gemm_qkv<<<dim3(3072 / 64, M_TOT / 128), 256, 0, stream>>>(
        xb, wqkvb, bq, bk, bv, qb, kb, vb, decay);

    int nblk = BATCH * NUM_HEADS * NCHUNK;  // 1024
    chunk_kv_mfma<<<nblk, 256, 0, stream>>>(kb, vb, statesb);
    prefix_kernel<<<dim3(16, 32), 256, 0, stream>>>(statesb);
    attn_mfma<<<nblk, 256, 0, stream>>>(qb, kb, vb, statesb, xb);   // bf16 attn into xb

    // output projection: 64x64 tiles, BK=128 (8 iters), 1024 blocks @ 4/CU, fp32 out
    gemm64_wo<<<dim3(1024 / 64, M_TOT / 64), 256, 0, stream>>>(xb, wob, bo, out);
}